// Round 7
// baseline (884.133 us; speedup 1.0000x reference)
//
#include <hip/hip_runtime.h>
#include <hip/hip_cooperative_groups.h>

namespace cg = cooperative_groups;

#define N_NODES 50000
#define N_EDGES 800000
#define HID 128
#define SLOT (N_NODES * HID)          // 6,400,000 floats per output block
#define W_STRIDE (HID * HID)          // 16384

// ---------------- workspace layout (byte offsets, 512-aligned) ----------------
#define OFF_CNT    0ul                      // 50000*4
#define OFF_DINV   200192ul                 // 50000*4
#define OFF_RPTR   400384ul                 // 50001*4
#define OFF_RFILL  600576ul                 // 50000*4
#define OFF_BSUM   800768ul                 // 256*4
#define OFF_BOFS   801792ul                 // 256*4
#define OFF_SRCS   802816ul                 // 800000*4
#define OFF_H_WS   4002816ul                // 50000*128*4 (optional)

// =================== fused preprocessing (ONE cooperative kernel) ===========
// phases: zero cnt | count degrees + copy x->slot1 | chunk scans | chunk-sum
// scan | finalize rptr/rfill/dinv | scatter srcs.  grid.sync() between
// dependent phases. 1024 blocks x 256 threads (light kernel, 8 blocks/CU
// capacity -> co-residency guaranteed; coop launch validates and errors out
// otherwise, in which case the host falls back to the 7-dispatch path).
__global__ void __launch_bounds__(256, 8)
k_preproc(const int* __restrict__ ei, const float* __restrict__ x,
          float* __restrict__ slot1, int* __restrict__ cnt,
          float* __restrict__ dinv, int* __restrict__ rptr,
          int* __restrict__ rfill, int* __restrict__ bsum,
          int* __restrict__ bofs, int* __restrict__ srcs) {
    cg::grid_group grid = cg::this_grid();
    const int tid = threadIdx.x;
    const int bid = blockIdx.x;
    const int nb  = gridDim.x;
    const int gstride = nb * 256;
    const int g = bid * 256 + tid;
    const int NCHUNK = (N_NODES + 255) / 256;   // 196

    __shared__ int sc[256];

    // A: zero degree counters
    for (int i = g; i < N_NODES; i += gstride) cnt[i] = 0;
    grid.sync();

    // B: count in-degrees; copy x -> embeddings[0] (independent, hides here)
    for (int e = g; e < N_EDGES; e += gstride)
        atomicAdd(&cnt[ei[N_EDGES + e]], 1);
    {
        const float4* x4  = (const float4*)x;
        float4*       s14 = (float4*)slot1;
        for (int i = g; i < SLOT / 4; i += gstride) s14[i] = x4[i];
    }
    grid.sync();

    // C: per-chunk (256 elems) exclusive scans
    for (int c = bid; c < NCHUNK; c += nb) {
        int idx = c * 256 + tid;
        int v = (idx < N_NODES) ? cnt[idx] : 0;
        sc[tid] = v;
        __syncthreads();
        for (int off = 1; off < 256; off <<= 1) {
            int t = (tid >= off) ? sc[tid - off] : 0;
            __syncthreads();
            sc[tid] += t;
            __syncthreads();
        }
        if (idx < N_NODES) rptr[idx] = sc[tid] - v;
        if (tid == 255) bsum[c] = sc[255];
        __syncthreads();
    }
    grid.sync();

    // D: scan the 196 chunk sums (block 0)
    if (bid == 0) {
        int v = (tid < NCHUNK) ? bsum[tid] : 0;
        sc[tid] = v;
        __syncthreads();
        for (int off = 1; off < 256; off <<= 1) {
            int t = (tid >= off) ? sc[tid - off] : 0;
            __syncthreads();
            sc[tid] += t;
            __syncthreads();
        }
        if (tid < NCHUNK) bofs[tid] = sc[tid] - v;
    }
    grid.sync();

    // E: finalize row pointers + dinv
    for (int i = g; i < N_NODES; i += gstride) {
        int r = rptr[i] + bofs[i >> 8];
        rptr[i]  = r;
        rfill[i] = r;
        int c = cnt[i];
        dinv[i] = (c > 0) ? rsqrtf((float)c) : 0.0f;
    }
    if (g == 0) rptr[N_NODES] = N_EDGES;
    grid.sync();

    // F: scatter src indices into CSR slots
    for (int e = g; e < N_EDGES; e += gstride) {
        int sv = ei[e];
        int d  = ei[N_EDGES + e];
        int pos = atomicAdd(&rfill[d], 1);
        srcs[pos] = sv;
    }
}

// ---------------- fallback preprocessing kernels (non-cooperative path) ----

__global__ void k_zero_cnt(int* __restrict__ cnt) {
    int i = blockIdx.x * blockDim.x + threadIdx.x;
    if (i < N_NODES) cnt[i] = 0;
}

__global__ void k_count(const int* __restrict__ ei, int* __restrict__ cnt) {
    int e = blockIdx.x * blockDim.x + threadIdx.x;
    if (e < N_EDGES) atomicAdd(&cnt[ei[N_EDGES + e]], 1);
}

__global__ void k_scan_block(const int* __restrict__ cnt, int* __restrict__ rptr,
                             int* __restrict__ bsum) {
    __shared__ int s[512];
    int tid = threadIdx.x;
    int gid = blockIdx.x * 512 + tid;
    int v = (gid < N_NODES) ? cnt[gid] : 0;
    s[tid] = v;
    __syncthreads();
    for (int off = 1; off < 512; off <<= 1) {
        int t = (tid >= off) ? s[tid - off] : 0;
        __syncthreads();
        s[tid] += t;
        __syncthreads();
    }
    if (gid < N_NODES) rptr[gid] = s[tid] - v;
    if (tid == 511) bsum[blockIdx.x] = s[511];
}

__global__ void k_scan_sums(const int* __restrict__ bsum, int* __restrict__ bofs, int nb) {
    __shared__ int s[128];
    int tid = threadIdx.x;
    int v = (tid < nb) ? bsum[tid] : 0;
    s[tid] = v;
    __syncthreads();
    for (int off = 1; off < 128; off <<= 1) {
        int t = (tid >= off) ? s[tid - off] : 0;
        __syncthreads();
        s[tid] += t;
        __syncthreads();
    }
    if (tid < nb) bofs[tid] = s[tid] - v;
}

__global__ void k_scan_add(int* __restrict__ rptr, int* __restrict__ rfill,
                           const int* __restrict__ bofs, const int* __restrict__ cnt,
                           float* __restrict__ dinv) {
    int gid = blockIdx.x * blockDim.x + threadIdx.x;
    if (gid < N_NODES) {
        int r = rptr[gid] + bofs[gid >> 9];
        rptr[gid] = r;
        rfill[gid] = r;
        int c = cnt[gid];
        dinv[gid] = (c > 0) ? rsqrtf((float)c) : 0.0f;
    }
    if (gid == 0) rptr[N_NODES] = N_EDGES;
}

__global__ void k_scatter(const int* __restrict__ ei, int* __restrict__ rfill,
                          int* __restrict__ srcs) {
    int e = blockIdx.x * blockDim.x + threadIdx.x;
    if (e < N_EDGES) {
        int sv = ei[e];
        int d  = ei[N_EDGES + e];
        int pos = atomicAdd(&rfill[d], 1);
        srcs[pos] = sv;
    }
}

__global__ void k_copy(const float* __restrict__ src, float* __restrict__ dst, int n4) {
    int i = blockIdx.x * blockDim.x + threadIdx.x;
    if (i < n4) ((float4*)dst)[i] = ((const float4*)src)[i];
}

// ---------------- dense transform: H = (X @ W) * dinv[row] ----------------
// 64-row x 64-col tile; W panel (128x64, 32 KB) staged once; X tile (64x128,
// 32 KB) XOR-swizzled. 64 KB LDS -> 2 blocks/CU.
__launch_bounds__(256, 2)
__global__ void k_gemm_scale(const float* __restrict__ X, const float* __restrict__ W,
                             const float* __restrict__ dinv, float* __restrict__ H) {
    __shared__ float sW[HID * 64];
    __shared__ float sX[64 * HID];
    int tid   = threadIdx.x;
    int chalf = blockIdx.x & 1;
    int row0  = (blockIdx.x >> 1) * 64;

    const float4* W4  = (const float4*)W;
    float4*       sW4 = (float4*)sW;
    for (int j = tid; j < 2048; j += 256) {
        int k  = j >> 4;
        int c4 = j & 15;
        sW4[j] = W4[k * 32 + chalf * 16 + c4];
    }

    const float4* X4  = (const float4*)X;
    float4*       sX4 = (float4*)sX;
    for (int j = tid; j < 2048; j += 256) {
        int r   = j >> 5;
        int c4  = j & 31;
        int row = row0 + r;
        float4 v = {0.f, 0.f, 0.f, 0.f};
        if (row < N_NODES) v = X4[row * 32 + c4];
        sX4[r * 32 + (c4 ^ ((r >> 3) & 7))] = v;
    }
    __syncthreads();

    int ty  = tid >> 4;
    int tx  = tid & 15;
    int swz = (ty >> 1) & 7;

    float4 acc[4];
    #pragma unroll
    for (int r = 0; r < 4; ++r) acc[r] = {0.f, 0.f, 0.f, 0.f};

    #pragma unroll 4
    for (int k0 = 0; k0 < HID; k0 += 4) {
        int k4 = k0 >> 2;
        float4 wv[4];
        #pragma unroll
        for (int kk = 0; kk < 4; ++kk)
            wv[kk] = sW4[(k0 + kk) * 16 + tx];
        float4 xv[4];
        #pragma unroll
        for (int r = 0; r < 4; ++r)
            xv[r] = sX4[(ty * 4 + r) * 32 + (k4 ^ swz)];
        #pragma unroll
        for (int r = 0; r < 4; ++r) {
            float xk0 = xv[r].x, xk1 = xv[r].y, xk2 = xv[r].z, xk3 = xv[r].w;
            acc[r].x += xk0 * wv[0].x + xk1 * wv[1].x + xk2 * wv[2].x + xk3 * wv[3].x;
            acc[r].y += xk0 * wv[0].y + xk1 * wv[1].y + xk2 * wv[2].y + xk3 * wv[3].y;
            acc[r].z += xk0 * wv[0].z + xk1 * wv[1].z + xk2 * wv[2].z + xk3 * wv[3].z;
            acc[r].w += xk0 * wv[0].w + xk1 * wv[1].w + xk2 * wv[2].w + xk3 * wv[3].w;
        }
    }

    float4* H4 = (float4*)H;
    #pragma unroll
    for (int r = 0; r < 4; ++r) {
        int row = row0 + ty * 4 + r;
        if (row < N_NODES) {
            float dv = dinv[row];
            float4 o = acc[r];
            o.x *= dv; o.y *= dv; o.z *= dv; o.w *= dv;
            H4[row * 32 + chalf * 16 + tx] = o;
        }
    }
}

// ---------------- aggregation (unchanged from round 6) ----------------
__global__ void k_agg(const float* __restrict__ H, const int* __restrict__ rptr,
                      const int* __restrict__ srcs, const float* __restrict__ dinv,
                      const float* __restrict__ bias, float* __restrict__ out0,
                      float* __restrict__ out1) {
    int wid  = (blockIdx.x * blockDim.x + threadIdx.x) >> 6;
    int lane = threadIdx.x & 63;
    if (wid >= N_NODES) return;
    int half = lane >> 5;
    int l32  = lane & 31;

    int beg = rptr[wid];
    int end = rptr[wid + 1];
    int deg = end - beg;

    const float4* H4 = (const float4*)H;

    float4 a0 = {0.f,0.f,0.f,0.f}, a1 = {0.f,0.f,0.f,0.f};
    float4 a2 = {0.f,0.f,0.f,0.f}, a3 = {0.f,0.f,0.f,0.f};

    int p = beg;
    int n8 = beg + (deg & ~7);
    for (; p < n8; p += 8) {
        int base = p + half * 4;
        int s0 = srcs[base + 0];
        int s1 = srcs[base + 1];
        int s2 = srcs[base + 2];
        int s3 = srcs[base + 3];
        float4 h0 = H4[s0 * 32 + l32];
        float4 h1 = H4[s1 * 32 + l32];
        float4 h2 = H4[s2 * 32 + l32];
        float4 h3 = H4[s3 * 32 + l32];
        a0.x += h0.x; a0.y += h0.y; a0.z += h0.z; a0.w += h0.w;
        a1.x += h1.x; a1.y += h1.y; a1.z += h1.z; a1.w += h1.w;
        a2.x += h2.x; a2.y += h2.y; a2.z += h2.z; a2.w += h2.w;
        a3.x += h3.x; a3.y += h3.y; a3.z += h3.z; a3.w += h3.w;
    }
    int rem   = deg & 7;
    int pairs = rem >> 1;
    for (int i = 0; i < pairs; ++i) {
        int e = p + 2 * i + half;
        float4 hv = H4[srcs[e] * 32 + l32];
        if (i == 0)      { a0.x += hv.x; a0.y += hv.y; a0.z += hv.z; a0.w += hv.w; }
        else if (i == 1) { a1.x += hv.x; a1.y += hv.y; a1.z += hv.z; a1.w += hv.w; }
        else             { a2.x += hv.x; a2.y += hv.y; a2.z += hv.z; a2.w += hv.w; }
    }
    if (rem & 1) {
        float4 hv = H4[srcs[end - 1] * 32 + l32];
        if (half == 0) { a3.x += hv.x; a3.y += hv.y; a3.z += hv.z; a3.w += hv.w; }
    }

    float4 s;
    s.x = a0.x + a1.x + a2.x + a3.x;
    s.y = a0.y + a1.y + a2.y + a3.y;
    s.z = a0.z + a1.z + a2.z + a3.z;
    s.w = a0.w + a1.w + a2.w + a3.w;
    s.x += __shfl_xor(s.x, 32);
    s.y += __shfl_xor(s.y, 32);
    s.z += __shfl_xor(s.z, 32);
    s.w += __shfl_xor(s.w, 32);

    if (half == 0) {
        float dv  = dinv[wid];
        float4 bb = ((const float4*)bias)[l32];
        float4 res;
        res.x = s.x * dv + bb.x;
        res.y = s.y * dv + bb.y;
        res.z = s.z * dv + bb.z;
        res.w = s.w * dv + bb.w;
        ((float4*)out0)[wid * 32 + l32] = res;
        if (out1) ((float4*)out1)[wid * 32 + l32] = res;
    }
}

// ---------------- launch ----------------

extern "C" void kernel_launch(void* const* d_in, const int* in_sizes, int n_in,
                              void* d_out, int out_size, void* d_ws, size_t ws_size,
                              hipStream_t stream) {
    const float* x  = (const float*)d_in[0];
    const int*   ei = (const int*)d_in[1];
    const float* Ws = (const float*)d_in[2];
    const float* bs = (const float*)d_in[3];
    float* out = (float*)d_out;
    char*  ws  = (char*)d_ws;

    int*   cnt   = (int*)  (ws + OFF_CNT);
    float* dinv  = (float*)(ws + OFF_DINV);
    int*   rptr  = (int*)  (ws + OFF_RPTR);
    int*   rfill = (int*)  (ws + OFF_RFILL);
    int*   bsum  = (int*)  (ws + OFF_BSUM);
    int*   bofs  = (int*)  (ws + OFF_BOFS);
    int*   srcs  = (int*)  (ws + OFF_SRCS);

    // output slots: [0]=x3(final), [1]=x0, [2]=x1, [3]=x2, [4]=x3
    float* slot0 = out;
    float* slot1 = out + 1l * SLOT;
    float* slot2 = out + 2l * SLOT;
    float* slot3 = out + 3l * SLOT;
    float* slot4 = out + 4l * SLOT;

    bool   h_in_ws = ws_size >= (size_t)(OFF_H_WS + (size_t)SLOT * 4);
    float* h = h_in_ws ? (float*)(ws + OFF_H_WS) : slot0;

    // ---- fused preprocessing (1 cooperative dispatch); fallback = 7 dispatches
    {
        const int*   ei_a    = ei;
        const float* x_a     = x;
        float*       slot1_a = slot1;
        void* args[] = {(void*)&ei_a, (void*)&x_a, (void*)&slot1_a,
                        (void*)&cnt, (void*)&dinv, (void*)&rptr, (void*)&rfill,
                        (void*)&bsum, (void*)&bofs, (void*)&srcs};
        hipError_t err = hipLaunchCooperativeKernel((void*)k_preproc,
                                                    dim3(1024), dim3(256),
                                                    args, 0, stream);
        if (err != hipSuccess) {
            (void)hipGetLastError();   // clear sticky error
            const int NB_NODE = (N_NODES + 255) / 256;
            const int NB_EDGE = (N_EDGES + 255) / 256;
            const int NB_SCAN = (N_NODES + 511) / 512;
            k_zero_cnt  <<<NB_NODE, 256, 0, stream>>>(cnt);
            k_count     <<<NB_EDGE, 256, 0, stream>>>(ei, cnt);
            k_scan_block<<<NB_SCAN, 512, 0, stream>>>(cnt, rptr, bsum);
            k_scan_sums <<<1, 128, 0, stream>>>(bsum, bofs, NB_SCAN);
            k_scan_add  <<<NB_NODE, 256, 0, stream>>>(rptr, rfill, bofs, cnt, dinv);
            k_scatter   <<<NB_EDGE, 256, 0, stream>>>(ei, rfill, srcs);
            k_copy      <<<SLOT / 4 / 256, 256, 0, stream>>>(x, slot1, SLOT / 4);
        }
    }

    const int NB_GEMM = 2 * ((N_NODES + 63) / 64);   // 1564
    const int NB_AGG  = (N_NODES + 3) / 4;           // 12500

    // ---- layer 1 ----
    k_gemm_scale<<<NB_GEMM, 256, 0, stream>>>(x, Ws + 0 * W_STRIDE, dinv, h);
    k_agg       <<<NB_AGG, 256, 0, stream>>>(h, rptr, srcs, dinv, bs + 0 * HID, slot2, nullptr);

    // ---- layer 2 ----
    k_gemm_scale<<<NB_GEMM, 256, 0, stream>>>(slot2, Ws + 1 * W_STRIDE, dinv, h);
    k_agg       <<<NB_AGG, 256, 0, stream>>>(h, rptr, srcs, dinv, bs + 1 * HID, slot3, nullptr);

    // ---- layer 3 ----
    k_gemm_scale<<<NB_GEMM, 256, 0, stream>>>(slot3, Ws + 2 * W_STRIDE, dinv, h);
    if (h_in_ws) {
        k_agg<<<NB_AGG, 256, 0, stream>>>(h, rptr, srcs, dinv, bs + 2 * HID, slot4, slot0);
    } else {
        k_agg<<<NB_AGG, 256, 0, stream>>>(h, rptr, srcs, dinv, bs + 2 * HID, slot4, nullptr);
        k_copy<<<SLOT / 4 / 256, 256, 0, stream>>>(slot4, slot0, SLOT / 4);
    }
}

// Round 8
// 391.359 us; speedup vs baseline: 2.2591x; 2.2591x over previous
//
#include <hip/hip_runtime.h>

#define N_NODES 50000
#define N_EDGES 800000
#define HID 128
#define SLOT (N_NODES * HID)          // 6,400,000 floats per output block
#define W_STRIDE (HID * HID)          // 16384

// ---------------- workspace layout (byte offsets, 512-aligned) ----------------
#define OFF_CNT    0ul                      // 50000*4
#define OFF_DINV   200192ul                 // 50000*4
#define OFF_RPTR   400384ul                 // 50001*4
#define OFF_RFILL  600576ul                 // 50000*4
#define OFF_BSUM   800768ul                 // 256*4
#define OFF_BOFS   801792ul                 // 256*4
#define OFF_SRCS   802816ul                 // 800000*4
#define OFF_H_WS   4002816ul                // 50000*128*4 (optional)

// ---------------- preprocessing kernels ----------------

__global__ void k_zero_cnt(int* __restrict__ cnt) {
    int i = blockIdx.x * blockDim.x + threadIdx.x;
    if (i < N_NODES) cnt[i] = 0;
}

// degree count + x -> slot1 copy fused (independent work, same dispatch)
__global__ void k_count(const int* __restrict__ ei, int* __restrict__ cnt,
                        const float* __restrict__ x, float* __restrict__ slot1) {
    int g = blockIdx.x * blockDim.x + threadIdx.x;
    if (g < N_EDGES) atomicAdd(&cnt[ei[N_EDGES + g]], 1);
    const float4* x4  = (const float4*)x;
    float4*       s14 = (float4*)slot1;
    int gs = gridDim.x * blockDim.x;
    for (int i = g; i < SLOT / 4; i += gs) s14[i] = x4[i];
}

__global__ void k_scan_block(const int* __restrict__ cnt, int* __restrict__ rptr,
                             int* __restrict__ bsum) {
    __shared__ int s[512];
    int tid = threadIdx.x;
    int gid = blockIdx.x * 512 + tid;
    int v = (gid < N_NODES) ? cnt[gid] : 0;
    s[tid] = v;
    __syncthreads();
    for (int off = 1; off < 512; off <<= 1) {
        int t = (tid >= off) ? s[tid - off] : 0;
        __syncthreads();
        s[tid] += t;
        __syncthreads();
    }
    if (gid < N_NODES) rptr[gid] = s[tid] - v;
    if (tid == 511) bsum[blockIdx.x] = s[511];
}

__global__ void k_scan_sums(const int* __restrict__ bsum, int* __restrict__ bofs, int nb) {
    __shared__ int s[128];
    int tid = threadIdx.x;
    int v = (tid < nb) ? bsum[tid] : 0;
    s[tid] = v;
    __syncthreads();
    for (int off = 1; off < 128; off <<= 1) {
        int t = (tid >= off) ? s[tid - off] : 0;
        __syncthreads();
        s[tid] += t;
        __syncthreads();
    }
    if (tid < nb) bofs[tid] = s[tid] - v;
}

__global__ void k_scan_add(int* __restrict__ rptr, int* __restrict__ rfill,
                           const int* __restrict__ bofs, const int* __restrict__ cnt,
                           float* __restrict__ dinv) {
    int gid = blockIdx.x * blockDim.x + threadIdx.x;
    if (gid < N_NODES) {
        int r = rptr[gid] + bofs[gid >> 9];
        rptr[gid] = r;
        rfill[gid] = r;
        int c = cnt[gid];
        dinv[gid] = (c > 0) ? rsqrtf((float)c) : 0.0f;
    }
    if (gid == 0) rptr[N_NODES] = N_EDGES;
}

__global__ void k_scatter(const int* __restrict__ ei, int* __restrict__ rfill,
                          int* __restrict__ srcs) {
    int e = blockIdx.x * blockDim.x + threadIdx.x;
    if (e < N_EDGES) {
        int sv = ei[e];
        int d  = ei[N_EDGES + e];
        int pos = atomicAdd(&rfill[d], 1);
        srcs[pos] = sv;
    }
}

__global__ void k_copy(const float* __restrict__ src, float* __restrict__ dst, int n4) {
    int i = blockIdx.x * blockDim.x + threadIdx.x;
    if (i < n4) ((float4*)dst)[i] = ((const float4*)src)[i];
}

// ---------------- dense transform: H = (X @ W) * dinv[row] ----------------
// 64-row x 64-col tile; W panel (128x64, 32 KB) staged once per block and
// reused over all k-steps; X tile (64x128, 32 KB) XOR-swizzled.
// 64 KB LDS -> 2 blocks/CU. (round-6 verified)
__launch_bounds__(256, 2)
__global__ void k_gemm_scale(const float* __restrict__ X, const float* __restrict__ W,
                             const float* __restrict__ dinv, float* __restrict__ H) {
    __shared__ float sW[HID * 64];
    __shared__ float sX[64 * HID];
    int tid   = threadIdx.x;
    int chalf = blockIdx.x & 1;
    int row0  = (blockIdx.x >> 1) * 64;

    const float4* W4  = (const float4*)W;
    float4*       sW4 = (float4*)sW;
    for (int j = tid; j < 2048; j += 256) {
        int k  = j >> 4;
        int c4 = j & 15;
        sW4[j] = W4[k * 32 + chalf * 16 + c4];
    }

    const float4* X4  = (const float4*)X;
    float4*       sX4 = (float4*)sX;
    for (int j = tid; j < 2048; j += 256) {
        int r   = j >> 5;
        int c4  = j & 31;
        int row = row0 + r;
        float4 v = {0.f, 0.f, 0.f, 0.f};
        if (row < N_NODES) v = X4[row * 32 + c4];
        sX4[r * 32 + (c4 ^ ((r >> 3) & 7))] = v;
    }
    __syncthreads();

    int ty  = tid >> 4;
    int tx  = tid & 15;
    int swz = (ty >> 1) & 7;

    float4 acc[4];
    #pragma unroll
    for (int r = 0; r < 4; ++r) acc[r] = {0.f, 0.f, 0.f, 0.f};

    #pragma unroll 4
    for (int k0 = 0; k0 < HID; k0 += 4) {
        int k4 = k0 >> 2;
        float4 wv[4];
        #pragma unroll
        for (int kk = 0; kk < 4; ++kk)
            wv[kk] = sW4[(k0 + kk) * 16 + tx];
        float4 xv[4];
        #pragma unroll
        for (int r = 0; r < 4; ++r)
            xv[r] = sX4[(ty * 4 + r) * 32 + (k4 ^ swz)];
        #pragma unroll
        for (int r = 0; r < 4; ++r) {
            float xk0 = xv[r].x, xk1 = xv[r].y, xk2 = xv[r].z, xk3 = xv[r].w;
            acc[r].x += xk0 * wv[0].x + xk1 * wv[1].x + xk2 * wv[2].x + xk3 * wv[3].x;
            acc[r].y += xk0 * wv[0].y + xk1 * wv[1].y + xk2 * wv[2].y + xk3 * wv[3].y;
            acc[r].z += xk0 * wv[0].z + xk1 * wv[1].z + xk2 * wv[2].z + xk3 * wv[3].z;
            acc[r].w += xk0 * wv[0].w + xk1 * wv[1].w + xk2 * wv[2].w + xk3 * wv[3].w;
        }
    }

    float4* H4 = (float4*)H;
    #pragma unroll
    for (int r = 0; r < 4; ++r) {
        int row = row0 + ty * 4 + r;
        if (row < N_NODES) {
            float dv = dinv[row];
            float4 o = acc[r];
            o.x *= dv; o.y *= dv; o.z *= dv; o.w *= dv;
            H4[row * 32 + chalf * 16 + tx] = o;
        }
    }
}

// ---------------- aggregation: out[v] = dinv[v] * sum_{src in row v} H[src] + b ----
// One wave per node. 4 lane-groups of 16; each group owns 4 edges per step
// (2 float4 per lane per row) -> 16 rows (8 KB) in flight per wave.
// Cross-group reduce via shfl_xor(16) + shfl_xor(32).
// NOTE: out0/out1 must NOT alias H.
__global__ void k_agg(const float* __restrict__ H, const int* __restrict__ rptr,
                      const int* __restrict__ srcs, const float* __restrict__ dinv,
                      const float* __restrict__ bias, float* __restrict__ out0,
                      float* __restrict__ out1) {
    int wid  = (blockIdx.x * blockDim.x + threadIdx.x) >> 6;
    int lane = threadIdx.x & 63;
    if (wid >= N_NODES) return;
    int grp = lane >> 4;           // 0..3
    int l16 = lane & 15;           // float4 col within half-row

    int beg = rptr[wid];
    int end = rptr[wid + 1];
    int deg = end - beg;

    const float4* H4 = (const float4*)H;

    float4 a[4][2];
    #pragma unroll
    for (int j = 0; j < 4; ++j) {
        a[j][0] = {0.f,0.f,0.f,0.f};
        a[j][1] = {0.f,0.f,0.f,0.f};
    }

    int p = beg;
    int n16 = beg + (deg & ~15);
    for (; p < n16; p += 16) {
        int base = p + grp * 4;
        #pragma unroll
        for (int j = 0; j < 4; ++j) {
            int s = srcs[base + j];
            float4 h0 = H4[s * 32 + l16];
            float4 h1 = H4[s * 32 + 16 + l16];
            a[j][0].x += h0.x; a[j][0].y += h0.y; a[j][0].z += h0.z; a[j][0].w += h0.w;
            a[j][1].x += h1.x; a[j][1].y += h1.y; a[j][1].z += h1.z; a[j][1].w += h1.w;
        }
    }
    // tail: each group takes every 4th remaining edge
    for (int e = p + grp; e < end; e += 4) {
        int s = srcs[e];
        float4 h0 = H4[s * 32 + l16];
        float4 h1 = H4[s * 32 + 16 + l16];
        a[0][0].x += h0.x; a[0][0].y += h0.y; a[0][0].z += h0.z; a[0][0].w += h0.w;
        a[0][1].x += h1.x; a[0][1].y += h1.y; a[0][1].z += h1.z; a[0][1].w += h1.w;
    }

    float4 s0, s1;
    s0.x = a[0][0].x + a[1][0].x + a[2][0].x + a[3][0].x;
    s0.y = a[0][0].y + a[1][0].y + a[2][0].y + a[3][0].y;
    s0.z = a[0][0].z + a[1][0].z + a[2][0].z + a[3][0].z;
    s0.w = a[0][0].w + a[1][0].w + a[2][0].w + a[3][0].w;
    s1.x = a[0][1].x + a[1][1].x + a[2][1].x + a[3][1].x;
    s1.y = a[0][1].y + a[1][1].y + a[2][1].y + a[3][1].y;
    s1.z = a[0][1].z + a[1][1].z + a[2][1].z + a[3][1].z;
    s1.w = a[0][1].w + a[1][1].w + a[2][1].w + a[3][1].w;

    #pragma unroll
    for (int d = 16; d <= 32; d <<= 1) {
        s0.x += __shfl_xor(s0.x, d); s0.y += __shfl_xor(s0.y, d);
        s0.z += __shfl_xor(s0.z, d); s0.w += __shfl_xor(s0.w, d);
        s1.x += __shfl_xor(s1.x, d); s1.y += __shfl_xor(s1.y, d);
        s1.z += __shfl_xor(s1.z, d); s1.w += __shfl_xor(s1.w, d);
    }

    if (lane < 16) {
        float dv  = dinv[wid];
        const float4* b4 = (const float4*)bias;
        float4 b0 = b4[l16], b1 = b4[16 + l16];
        float4 r0, r1;
        r0.x = s0.x * dv + b0.x; r0.y = s0.y * dv + b0.y;
        r0.z = s0.z * dv + b0.z; r0.w = s0.w * dv + b0.w;
        r1.x = s1.x * dv + b1.x; r1.y = s1.y * dv + b1.y;
        r1.z = s1.z * dv + b1.z; r1.w = s1.w * dv + b1.w;
        float4* o0 = (float4*)out0;
        o0[wid * 32 + l16]      = r0;
        o0[wid * 32 + 16 + l16] = r1;
        if (out1) {
            float4* o1 = (float4*)out1;
            o1[wid * 32 + l16]      = r0;
            o1[wid * 32 + 16 + l16] = r1;
        }
    }
}

// ---------------- launch ----------------

extern "C" void kernel_launch(void* const* d_in, const int* in_sizes, int n_in,
                              void* d_out, int out_size, void* d_ws, size_t ws_size,
                              hipStream_t stream) {
    const float* x  = (const float*)d_in[0];
    const int*   ei = (const int*)d_in[1];
    const float* Ws = (const float*)d_in[2];
    const float* bs = (const float*)d_in[3];
    float* out = (float*)d_out;
    char*  ws  = (char*)d_ws;

    int*   cnt   = (int*)  (ws + OFF_CNT);
    float* dinv  = (float*)(ws + OFF_DINV);
    int*   rptr  = (int*)  (ws + OFF_RPTR);
    int*   rfill = (int*)  (ws + OFF_RFILL);
    int*   bsum  = (int*)  (ws + OFF_BSUM);
    int*   bofs  = (int*)  (ws + OFF_BOFS);
    int*   srcs  = (int*)  (ws + OFF_SRCS);

    // output slots: [0]=x3(final), [1]=x0, [2]=x1, [3]=x2, [4]=x3
    float* slot0 = out;
    float* slot1 = out + 1l * SLOT;
    float* slot2 = out + 2l * SLOT;
    float* slot3 = out + 3l * SLOT;
    float* slot4 = out + 4l * SLOT;

    bool   h_in_ws = ws_size >= (size_t)(OFF_H_WS + (size_t)SLOT * 4);
    float* h = h_in_ws ? (float*)(ws + OFF_H_WS) : slot0;

    const int NB_NODE = (N_NODES + 255) / 256;   // 196
    const int NB_EDGE = (N_EDGES + 255) / 256;   // 3125
    const int NB_SCAN = (N_NODES + 511) / 512;   // 98

    // ---- preprocessing: degrees(+x copy), dinv, CSR by dst ----
    k_zero_cnt  <<<NB_NODE, 256, 0, stream>>>(cnt);
    k_count     <<<NB_EDGE, 256, 0, stream>>>(ei, cnt, x, slot1);
    k_scan_block<<<NB_SCAN, 512, 0, stream>>>(cnt, rptr, bsum);
    k_scan_sums <<<1, 128, 0, stream>>>(bsum, bofs, NB_SCAN);
    k_scan_add  <<<NB_NODE, 256, 0, stream>>>(rptr, rfill, bofs, cnt, dinv);
    k_scatter   <<<NB_EDGE, 256, 0, stream>>>(ei, rfill, srcs);

    const int NB_GEMM = 2 * ((N_NODES + 63) / 64);   // 1564
    const int NB_AGG  = (N_NODES + 3) / 4;           // 12500

    // ---- layer 1 ----
    k_gemm_scale<<<NB_GEMM, 256, 0, stream>>>(x, Ws + 0 * W_STRIDE, dinv, h);
    k_agg       <<<NB_AGG, 256, 0, stream>>>(h, rptr, srcs, dinv, bs + 0 * HID, slot2, nullptr);

    // ---- layer 2 ----
    k_gemm_scale<<<NB_GEMM, 256, 0, stream>>>(slot2, Ws + 1 * W_STRIDE, dinv, h);
    k_agg       <<<NB_AGG, 256, 0, stream>>>(h, rptr, srcs, dinv, bs + 1 * HID, slot3, nullptr);

    // ---- layer 3 ----
    k_gemm_scale<<<NB_GEMM, 256, 0, stream>>>(slot3, Ws + 2 * W_STRIDE, dinv, h);
    if (h_in_ws) {
        k_agg<<<NB_AGG, 256, 0, stream>>>(h, rptr, srcs, dinv, bs + 2 * HID, slot4, slot0);
    } else {
        k_agg<<<NB_AGG, 256, 0, stream>>>(h, rptr, srcs, dinv, bs + 2 * HID, slot4, nullptr);
        k_copy<<<SLOT / 4 / 256, 256, 0, stream>>>(slot4, slot0, SLOT / 4);
    }
}